// Round 1
// 282.818 us; speedup vs baseline: 1.0688x; 1.0688x over previous
//
#include <hip/hip_runtime.h>
#include <hip/hip_bf16.h>
#include <stdint.h>

// GCN 2-layer forward: out = A_hat @ relu(A_hat @ (X W1^T + b1)) W2^T + b2
// A_hat = D^-1/2 (A + I) D^-1/2, pull-based CSR aggregation.
// GEMMs use bf16 MFMA (16x16x32), fp32 accumulate; epilogue pre-scales rows by
// dis[n] and stores H' in BF16. Aggregation gathers bf16, accumulates fp32;
// agg1 emits R1 in bf16 (gemm2 consumes bf16 directly).
// CSR build = two-level counting sort with ZERO global atomics.
// Agg v2: wide-gather — 16 lanes x 16B (or 8B) per edge, 4 edges per load
// instruction, 4 loads in flight, cross-group shfl_xor butterfly reduce.
// (v1 was 64x4B dword gathers, 20 VGPRs, latency-bound at 43% HBM.)

#define TPB 256
#define NBLK_C 256            // edge chunks (blocks) in hist/scatter passes
#define TPB_C 1024            // threads per chunk block
#define MAX_NB 2048           // max coarse buckets (N <= 262144)

typedef __attribute__((ext_vector_type(8))) __bf16 bf16x8;
typedef __attribute__((ext_vector_type(4))) float f32x4;

__device__ __forceinline__ float bf16lo(unsigned u) { return __uint_as_float(u << 16); }
__device__ __forceinline__ float bf16hi(unsigned u) { return __uint_as_float(u & 0xffff0000u); }
__device__ __forceinline__ unsigned short f2bf(float f) {
    unsigned u = __float_as_uint(f);
    return (unsigned short)((u + 0x7fff + ((u >> 16) & 1)) >> 16);  // RNE
}

// ---------------------------------------------------------------------------
// dtype probe: edge_index may arrive as int32 or int64. If int64 (values < 2^31,
// non-negative), every odd 32-bit word of the first 64 entries is 0.
__global__ void detect64_kernel(const int* __restrict__ ei32, int* __restrict__ flag) {
    if (threadIdx.x == 0 && blockIdx.x == 0) {
        int is64 = 1;
        for (int t = 0; t < 64; ++t) {
            if (ei32[2 * t + 1] != 0) { is64 = 0; break; }
        }
        *flag = is64;
    }
}

// ---------------------------------------------------------------------------
// K1: unpack edge_index -> row32/col32 AND per-block coarse-bucket histogram
// (bucket = row >> 7). LDS atomics only; hist[bin*NBLK_C + b] written once.
__global__ __launch_bounds__(TPB_C) void hist_extract_kernel(const void* __restrict__ ei, int E,
                                                             int CH,
                                                             const int* __restrict__ flag,
                                                             int* __restrict__ row32,
                                                             int* __restrict__ col32,
                                                             int* __restrict__ hist,
                                                             int NB, int N) {
    __shared__ int h[MAX_NB];
    int tid = threadIdx.x;
    for (int bin = tid; bin < NB; bin += TPB_C) h[bin] = 0;
    __syncthreads();

    int b = blockIdx.x;
    int s = b * CH;
    int end = min(E, s + CH);
    int is64 = *flag;
    unsigned uN = (unsigned)N;
    if (is64) {
        const long long* p = (const long long*)ei;
        for (int e = s + tid; e < end; e += TPB_C) {
            int r = (int)p[e];
            int c = (int)p[E + e];
            row32[e] = r;
            col32[e] = c;
            if ((unsigned)r < uN && (unsigned)c < uN) atomicAdd(&h[r >> 7], 1);
        }
    } else {
        const int* p = (const int*)ei;
        for (int e = s + tid; e < end; e += TPB_C) {
            int r = p[e];
            int c = p[E + e];
            row32[e] = r;
            col32[e] = c;
            if ((unsigned)r < uN && (unsigned)c < uN) atomicAdd(&h[r >> 7], 1);
        }
    }
    __syncthreads();
    for (int bin = tid; bin < NB; bin += TPB_C) hist[bin * NBLK_C + b] = h[bin];
}

// ---------------------------------------------------------------------------
// K2: per-bucket exclusive scan across the NBLK_C block histograms (in place);
// emits binTotal[bin]. One block per bucket, TPB == NBLK_C.
__global__ __launch_bounds__(NBLK_C) void colscan_kernel(int* __restrict__ hist,
                                                         int* __restrict__ binTotal) {
    __shared__ int sm[NBLK_C];
    int bin = blockIdx.x;
    int tid = threadIdx.x;
    int v = hist[bin * NBLK_C + tid];
    sm[tid] = v;
    __syncthreads();
    for (int o = 1; o < NBLK_C; o <<= 1) {
        int x = (tid >= o) ? sm[tid - o] : 0;
        __syncthreads();
        sm[tid] += x;
        __syncthreads();
    }
    hist[bin * NBLK_C + tid] = sm[tid] - v;  // exclusive within bucket
    if (tid == NBLK_C - 1) binTotal[bin] = sm[NBLK_C - 1];
}

// ---------------------------------------------------------------------------
// K3: exclusive scan over bucket totals -> bucketStart.  NB <= 1024.
__global__ __launch_bounds__(1024) void binscan_kernel(const int* __restrict__ binTotal,
                                                       int* __restrict__ bucketStart, int NB) {
    __shared__ int sm[1024];
    int tid = threadIdx.x;
    int v = (tid < NB) ? binTotal[tid] : 0;
    sm[tid] = v;
    __syncthreads();
    for (int o = 1; o < 1024; o <<= 1) {
        int x = (tid >= o) ? sm[tid - o] : 0;
        __syncthreads();
        sm[tid] += x;
        __syncthreads();
    }
    if (tid < NB) bucketStart[tid] = sm[tid] - v;
}

// ---------------------------------------------------------------------------
// K4: place edges into coarse buckets. Per-block LDS cursors seeded from
// bucketStart + per-block exclusive prefix; packed = (col<<7) | (row&127).
__global__ __launch_bounds__(TPB_C) void scatter_kernel(const int* __restrict__ row32,
                                                        const int* __restrict__ col32, int E,
                                                        int CH,
                                                        const int* __restrict__ hist,
                                                        const int* __restrict__ bucketStart,
                                                        int* __restrict__ bucketed,
                                                        int NB, int N) {
    __shared__ int cur[MAX_NB];
    int tid = threadIdx.x;
    int b = blockIdx.x;
    for (int bin = tid; bin < NB; bin += TPB_C)
        cur[bin] = bucketStart[bin] + hist[bin * NBLK_C + b];
    __syncthreads();

    int s = b * CH;
    int end = min(E, s + CH);
    unsigned uN = (unsigned)N;
    for (int e = s + tid; e < end; e += TPB_C) {
        int r = row32[e];
        int c = col32[e];
        if ((unsigned)r < uN && (unsigned)c < uN) {
            int pos = atomicAdd(&cur[r >> 7], 1);
            bucketed[pos] = (c << 7) | (r & 127);
        }
    }
}

// ---------------------------------------------------------------------------
// K5: fine counting sort inside each 128-row bucket. Emits offs/cnt/dis for
// the bucket's rows and the final csr segment (all LDS atomics).
__global__ __launch_bounds__(TPB) void finecsr_kernel(const int* __restrict__ bucketed,
                                                      const int* __restrict__ bucketStart,
                                                      const int* __restrict__ binTotal,
                                                      int* __restrict__ offs,
                                                      int* __restrict__ cnt,
                                                      float* __restrict__ dis,
                                                      int* __restrict__ csr, int N) {
    __shared__ int c128[128];
    __shared__ int cur128[128];
    __shared__ int sm[TPB];
    int bin = blockIdx.x;
    int tid = threadIdx.x;
    int s = bucketStart[bin];
    int m = binTotal[bin];

    if (tid < 128) c128[tid] = 0;
    __syncthreads();
    for (int i = tid; i < m; i += TPB) atomicAdd(&c128[bucketed[s + i] & 127], 1);
    __syncthreads();

    int v = (tid < 128) ? c128[tid] : 0;
    sm[tid] = v;
    __syncthreads();
    for (int o = 1; o < 128; o <<= 1) {
        int x = (tid >= o) ? sm[tid - o] : 0;
        __syncthreads();
        sm[tid] += x;
        __syncthreads();
    }
    if (tid < 128) {
        int excl = sm[tid] - v;
        int r = bin * 128 + tid;
        if (r < N) {
            offs[r] = s + excl;
            cnt[r] = v;
            dis[r] = rsqrtf((float)v + 1.0f);
        }
        cur128[tid] = s + excl;
    }
    __syncthreads();
    for (int i = tid; i < m; i += TPB) {
        int p = bucketed[s + i];
        int pos = atomicAdd(&cur128[p & 127], 1);
        csr[pos] = p >> 7;
    }
}

// ---------------------------------------------------------------------------
// MFMA bf16 GEMM: Hb[r, :] = bf16( dis[r] * (X[r,:] @ W^T + b) ),  K = 128.
// BM=128 rows/block, BN = 128 or 64 cols. X (fp32 or bf16) and W (fp32) are
// cast to bf16 and staged in LDS with row stride 136 shorts (272 B) so the
// per-fragment ds_read_b128 spreads evenly over all 32 banks.
// 4 waves: BN=128 -> each wave 64x64 (4x4 16x16 tiles); BN=64 -> 32x64 (2x4).
// Fragment layouts (verified, cdna_hip_programming §3):
//   A[m=lane&15][k=(lane>>4)*8+j], B[n=lane&15][k=(lane>>4)*8+j],
//   D: col=lane&15, row=(lane>>4)*4+reg.
template <int BN, bool INB16>
__global__ __launch_bounds__(256, 2) void gemm_mfma_kernel(const void* __restrict__ Xp,
                                                           const float* __restrict__ W,
                                                           const float* __restrict__ bias,
                                                           const float* __restrict__ dis,
                                                           unsigned short* __restrict__ Hb,
                                                           int N) {
    constexpr int XST = 136;  // padded LDS row stride (shorts); 272 B ≡ 4 banks shift/row
    __shared__ unsigned short Xs[128 * XST];
    __shared__ unsigned short Ws[BN * XST];

    const int tid = threadIdx.x;
    const int r0 = blockIdx.x * 128;

    // ---- stage X tile (128 x 128) as bf16
    if (INB16) {
        const ushort4* Xv = (const ushort4*)Xp;
        for (int idx = tid; idx < 128 * 32; idx += 256) {
            int row = idx >> 5, q = idx & 31;
            int rg = r0 + row;
            if (rg >= N) rg = N - 1;
            *(ushort4*)&Xs[row * XST + q * 4] = Xv[(size_t)rg * 32 + q];
        }
    } else {
        const float4* Xv = (const float4*)Xp;
        for (int idx = tid; idx < 128 * 32; idx += 256) {
            int row = idx >> 5, q = idx & 31;
            int rg = r0 + row;
            if (rg >= N) rg = N - 1;
            float4 v = Xv[(size_t)rg * 32 + q];
            ushort4 s = make_ushort4(f2bf(v.x), f2bf(v.y), f2bf(v.z), f2bf(v.w));
            *(ushort4*)&Xs[row * XST + q * 4] = s;
        }
    }
    // ---- stage W tile (BN x 128) as bf16
    {
        const float4* Wv = (const float4*)W;
        for (int idx = tid; idx < BN * 32; idx += 256) {
            int n = idx >> 5, q = idx & 31;
            float4 v = Wv[n * 32 + q];
            ushort4 s = make_ushort4(f2bf(v.x), f2bf(v.y), f2bf(v.z), f2bf(v.w));
            *(ushort4*)&Ws[n * XST + q * 4] = s;
        }
    }
    __syncthreads();

    constexpr int RT = (BN == 128) ? 4 : 2;  // 16-row tiles per wave
    constexpr int CT = 4;                    // 16-col tiles per wave
    const int wave = tid >> 6, lane = tid & 63;
    const int l15 = lane & 15, q8 = lane >> 4;
    const int row0 = (BN == 128) ? (wave & 1) * 64 : wave * 32;
    const int col0 = (BN == 128) ? (wave >> 1) * 64 : 0;

    f32x4 zero = {0.f, 0.f, 0.f, 0.f};
    f32x4 acc[RT][CT];
#pragma unroll
    for (int rt = 0; rt < RT; ++rt)
#pragma unroll
        for (int ct = 0; ct < CT; ++ct) acc[rt][ct] = zero;

#pragma unroll
    for (int ks = 0; ks < 4; ++ks) {
        int ko = ks * 32 + q8 * 8;
        bf16x8 a[RT], b[CT];
#pragma unroll
        for (int rt = 0; rt < RT; ++rt)
            a[rt] = *(const bf16x8*)&Xs[(row0 + rt * 16 + l15) * XST + ko];
#pragma unroll
        for (int ct = 0; ct < CT; ++ct)
            b[ct] = *(const bf16x8*)&Ws[(col0 + ct * 16 + l15) * XST + ko];
#pragma unroll
        for (int rt = 0; rt < RT; ++rt)
#pragma unroll
            for (int ct = 0; ct < CT; ++ct)
                acc[rt][ct] = __builtin_amdgcn_mfma_f32_16x16x32_bf16(
                    a[rt], b[ct], acc[rt][ct], 0, 0, 0);
    }

    // ---- epilogue: (+bias[col]) * dis[row], pack bf16
    float bv[CT];
#pragma unroll
    for (int ct = 0; ct < CT; ++ct) bv[ct] = bias[col0 + ct * 16 + l15];
#pragma unroll
    for (int rt = 0; rt < RT; ++rt)
#pragma unroll
        for (int r = 0; r < 4; ++r) {
            int row = r0 + row0 + rt * 16 + q8 * 4 + r;
            if (row < N) {
                float dn = dis[row];
#pragma unroll
                for (int ct = 0; ct < CT; ++ct)
                    Hb[(size_t)row * BN + col0 + ct * 16 + l15] =
                        f2bf((acc[rt][ct][r] + bv[ct]) * dn);
            }
        }
}

// ---------------------------------------------------------------------------
// Pull aggregation over pre-scaled bf16 H' (H'[n] = dis[n]*(XW+b)[n]):
//   out[i] = dis[i] * (H'[i] + sum_e H'[col_e]),  optional relu.
// v2 wide-gather layout: one wave per node; lane = 16*g + fl where
//   g  = edge subgroup (0..3)  — 4 edges serviced per load instruction
//   fl = feature granule (0..15) — 16B (F=128, uint4) or 8B (F=64, uint2)
// Each gather load is a dwordx4/dwordx2 covering a FULL source row per
// 16-lane group -> 1KB (512B) per instruction, 4 independent loads in
// flight per 16-edge step (vs 8x256B dword rounds in v1; VGPR=20 capped
// MLP there). Tail is branch-free: shfl idx clamped &63 -> masked fma x0.
// Cross-group butterfly (shfl_xor 16,32) folds the 4 partial sums.
// OB16: pack output to bf16 (for R1 feeding the bf16 MFMA gemm2).
template <int F, bool RELU, bool OB16>
__global__ __launch_bounds__(TPB) void agg_kernel(const unsigned short* __restrict__ Hb,
                                                  const int* __restrict__ csr,
                                                  const int* __restrict__ offs,
                                                  const int* __restrict__ cnt,
                                                  const float* __restrict__ dis,
                                                  void* __restrict__ outp, int N) {
    constexpr int FPL = F / 16;      // features per lane (8 or 4)
    constexpr int NW = FPL / 2;      // dwords per lane (4 or 2)
    constexpr int RS = F / 2;        // row stride in dwords (64 or 32)

    int w = (blockIdx.x * TPB + threadIdx.x) >> 6;
    if (w >= N) return;  // wave-uniform: whole wave exits together
    int lane = threadIdx.x & 63;
    int g = lane >> 4;               // edge subgroup
    int fl = lane & 15;              // feature-granule index

    float di = dis[w];
    int s = offs[w];
    int d = cnt[w];

    const unsigned* Hu = (const unsigned*)Hb;

    // ---- self term (counted once: group 0 only, others init to 0)
    float acc[FPL];
    {
        unsigned su[NW];
        if constexpr (NW == 4) {
            uint4 v = *(const uint4*)&Hu[(size_t)w * RS + fl * NW];
            su[0] = v.x; su[1] = v.y; su[2] = v.z; su[3] = v.w;
        } else {
            uint2 v = *(const uint2*)&Hu[(size_t)w * RS + fl * NW];
            su[0] = v.x; su[1] = v.y;
        }
        float sm = (g == 0) ? 1.0f : 0.0f;
#pragma unroll
        for (int t = 0; t < NW; ++t) {
            acc[2 * t] = sm * bf16lo(su[t]);
            acc[2 * t + 1] = sm * bf16hi(su[t]);
        }
    }

    for (int base = 0; base < d; base += 64) {
        int rem = d - base;
        if (rem > 64) rem = 64;
        int cl = (lane < rem) ? csr[s + base + lane] : 0;  // coalesced chunk load

        for (int e = 0; e < rem; e += 16) {  // 16 edges / step, 4 wide loads
            int cc[4];
            float m[4];
#pragma unroll
            for (int k = 0; k < 4; ++k) {
                int idx = e + k * 4 + g;
                cc[k] = __shfl(cl, idx & 63);          // wrap -> masked below
                m[k] = (idx < rem) ? 1.0f : 0.0f;
            }
            unsigned u[4][NW];
#pragma unroll
            for (int k = 0; k < 4; ++k) {
                if constexpr (NW == 4) {
                    uint4 v = *(const uint4*)&Hu[(size_t)cc[k] * RS + fl * NW];
                    u[k][0] = v.x; u[k][1] = v.y; u[k][2] = v.z; u[k][3] = v.w;
                } else {
                    uint2 v = *(const uint2*)&Hu[(size_t)cc[k] * RS + fl * NW];
                    u[k][0] = v.x; u[k][1] = v.y;
                }
            }
#pragma unroll
            for (int k = 0; k < 4; ++k)
#pragma unroll
                for (int t = 0; t < NW; ++t) {
                    acc[2 * t]     = fmaf(m[k], bf16lo(u[k][t]), acc[2 * t]);
                    acc[2 * t + 1] = fmaf(m[k], bf16hi(u[k][t]), acc[2 * t + 1]);
                }
        }
    }

    // ---- fold the 4 edge-subgroups (lanes fl, fl+16, fl+32, fl+48 share features)
#pragma unroll
    for (int off = 16; off < 64; off <<= 1)
#pragma unroll
        for (int j = 0; j < FPL; ++j) acc[j] += __shfl_xor(acc[j], off);

#pragma unroll
    for (int j = 0; j < FPL; ++j) {
        acc[j] *= di;
        if (RELU) acc[j] = fmaxf(acc[j], 0.0f);
    }

    // ---- store: lanes 0..15 hold the full row (256B / 128B contiguous)
    if (lane < 16) {
        if constexpr (OB16) {
            unsigned dw[NW];
#pragma unroll
            for (int t = 0; t < NW; ++t)
                dw[t] = (unsigned)f2bf(acc[2 * t]) | ((unsigned)f2bf(acc[2 * t + 1]) << 16);
            unsigned* op = (unsigned*)outp;
            if constexpr (NW == 4) {
                *(uint4*)&op[(size_t)w * RS + fl * NW] = make_uint4(dw[0], dw[1], dw[2], dw[3]);
            } else {
                *(uint2*)&op[(size_t)w * RS + fl * NW] = make_uint2(dw[0], dw[1]);
            }
        } else {
            float4* op = (float4*)outp;
            if constexpr (FPL == 4) {
                op[(size_t)w * 16 + fl] = make_float4(acc[0], acc[1], acc[2], acc[3]);
            } else {
                op[(size_t)w * 32 + fl * 2]     = make_float4(acc[0], acc[1], acc[2], acc[3]);
                op[(size_t)w * 32 + fl * 2 + 1] = make_float4(acc[4], acc[5], acc[6], acc[7]);
            }
        }
    }
}

// ---------------------------------------------------------------------------
extern "C" void kernel_launch(void* const* d_in, const int* in_sizes, int n_in,
                              void* d_out, int out_size, void* d_ws, size_t ws_size,
                              hipStream_t stream) {
    const float* x  = (const float*)d_in[0];
    const void*  ei = d_in[1];
    const float* W1 = (const float*)d_in[3];
    const float* b1 = (const float*)d_in[4];
    const float* W2 = (const float*)d_in[5];
    const float* b2 = (const float*)d_in[6];
    float* out = (float*)d_out;

    const int IN = 128, HID = 128;
    const int N = in_sizes[0] / IN;
    const int E = in_sizes[1] / 2;
    const int NB = (N + 127) >> 7;                 // coarse buckets (rows/128)
    const int CH = (E + NBLK_C - 1) / NBLK_C;      // edges per chunk block

    char* ws = (char*)d_ws;
    size_t off = 0;
    auto alloc = [&](size_t bytes) -> void* {
        void* p = (void*)(ws + off);
        off += (bytes + 255) & ~(size_t)255;
        return p;
    };
    int*   flag     = (int*)alloc(256);
    int*   cnt      = (int*)alloc((size_t)N * 4);
    int*   offs     = (int*)alloc((size_t)N * 4);
    float* dis      = (float*)alloc((size_t)N * 4);
    int*   row32    = (int*)alloc((size_t)E * 4);
    int*   col32    = (int*)alloc((size_t)E * 4);
    int*   bucketed = (int*)alloc((size_t)E * 4);
    int*   csr      = (int*)alloc((size_t)E * 4);
    int*   hist     = (int*)alloc((size_t)NB * NBLK_C * 4);
    int*   binTotal = (int*)alloc((size_t)NB * 4);
    int*   bStart   = (int*)alloc((size_t)NB * 4);
    unsigned short* H1b = (unsigned short*)alloc((size_t)N * HID * 2);  // bf16
    unsigned short* R1b = (unsigned short*)alloc((size_t)N * HID * 2);  // bf16
    unsigned short* H2b = H1b;  // reuse: H1b dead after agg1

    detect64_kernel<<<1, 64, 0, stream>>>((const int*)ei, flag);

    // ---- CSR build: counting sort, zero global atomics
    hist_extract_kernel<<<NBLK_C, TPB_C, 0, stream>>>(ei, E, CH, flag, row32, col32,
                                                      hist, NB, N);
    colscan_kernel<<<NB, NBLK_C, 0, stream>>>(hist, binTotal);
    binscan_kernel<<<1, 1024, 0, stream>>>(binTotal, bStart, NB);
    scatter_kernel<<<NBLK_C, TPB_C, 0, stream>>>(row32, col32, E, CH, hist, bStart,
                                                 bucketed, NB, N);
    finecsr_kernel<<<NB, TPB, 0, stream>>>(bucketed, bStart, binTotal,
                                           offs, cnt, dis, csr, N);

    int ngrid = (N + 127) / 128;

    // layer 1: H1b = bf16(dis .* (X@W1^T + b1)) ; R1b = bf16(relu(dis .* (self+gather)))
    gemm_mfma_kernel<128, false><<<ngrid, 256, 0, stream>>>(x, W1, b1, dis, H1b, N);
    agg_kernel<128, true, true><<<(N + 3) / 4, TPB, 0, stream>>>(H1b, csr, offs, cnt,
                                                                 dis, R1b, N);

    // layer 2: H2b = bf16(dis .* (R1b@W2^T + b2)) ; out = dis .* (self + gather)
    gemm_mfma_kernel<64, true><<<ngrid, 256, 0, stream>>>(R1b, W2, b2, dis, H2b, N);
    agg_kernel<64, false, false><<<(N + 3) / 4, TPB, 0, stream>>>(H2b, csr, offs, cnt,
                                                                  dis, out, N);
}

// Round 2
// 274.304 us; speedup vs baseline: 1.1020x; 1.0310x over previous
//
#include <hip/hip_runtime.h>
#include <hip/hip_bf16.h>
#include <stdint.h>

// GCN 2-layer forward: out = A_hat @ relu(A_hat @ (X W1^T + b1)) W2^T + b2
// A_hat = D^-1/2 (A + I) D^-1/2, pull-based CSR aggregation.
// GEMMs use bf16 MFMA (16x16x32), fp32 accumulate; epilogue pre-scales rows by
// dis[n], stores H' in BF16, and zeroes sentinel row N (tail gathers hit it).
// Agg v3: wide-gather (16 lanes x 16B, 4 edges/load) + v_pk_add_f32 packed
// accumulate (3 VALU/dword vs 5 in v2: no mask-fma, tail edges gather the
// zero row) + self-load predicated to group 0 + 2-step software pipeline
// (8 loads in flight). CSR build = two-level counting sort, zero global
// atomics; dtype probe folded into hist (ballot), bucket-total scan folded
// into scatter/finecsr (removes 2 launches).

#define TPB 256
#define NBLK_C 256            // edge chunks (blocks) in hist/scatter passes
#define TPB_C 1024            // threads per chunk block
#define MAX_NB 2048           // max coarse buckets (scan paths assume NB <= 1024)

typedef __attribute__((ext_vector_type(8))) __bf16 bf16x8;
typedef __attribute__((ext_vector_type(4))) float f32x4;
typedef __attribute__((ext_vector_type(2))) float f32x2;

__device__ __forceinline__ float bf16lo(unsigned u) { return __uint_as_float(u << 16); }
__device__ __forceinline__ float bf16hi(unsigned u) { return __uint_as_float(u & 0xffff0000u); }
__device__ __forceinline__ unsigned short f2bf(float f) {
    unsigned u = __float_as_uint(f);
    return (unsigned short)((u + 0x7fff + ((u >> 16) & 1)) >> 16);  // RNE
}
// packed 2xfp32 add (VOP3P, full-rate on CDNA2+): one instr for both bf16 halves
__device__ __forceinline__ f32x2 pk_add(f32x2 a, f32x2 b) {
    f32x2 d;
    asm("v_pk_add_f32 %0, %1, %2" : "=v"(d) : "v"(a), "v"(b));
    return d;
}

// ---------------------------------------------------------------------------
// K1: unpack edge_index -> row32/col32 AND per-block coarse-bucket histogram
// (bucket = row >> 7). Dtype probe (int64 vs int32) done per-block by wave 0:
// int64 inputs (values < 2^31) have every odd 32-bit word of the first 64
// entries == 0. All blocks compute the same answer -> no race, no extra launch.
__global__ __launch_bounds__(TPB_C) void hist_extract_kernel(const void* __restrict__ ei, int E,
                                                             int CH,
                                                             int* __restrict__ row32,
                                                             int* __restrict__ col32,
                                                             int* __restrict__ hist,
                                                             int NB, int N) {
    __shared__ int h[MAX_NB];
    __shared__ int s_is64;
    int tid = threadIdx.x;
    if (tid < 64) {
        int x = ((const int*)ei)[2 * tid + 1];
        unsigned long long b = __ballot(x != 0);
        if (tid == 0) s_is64 = (b == 0ull);
    }
    for (int bin = tid; bin < NB; bin += TPB_C) h[bin] = 0;
    __syncthreads();

    int b = blockIdx.x;
    int s = b * CH;
    int end = min(E, s + CH);
    int is64 = s_is64;
    unsigned uN = (unsigned)N;
    if (is64) {
        const long long* p = (const long long*)ei;
        for (int e = s + tid; e < end; e += TPB_C) {
            int r = (int)p[e];
            int c = (int)p[E + e];
            row32[e] = r;
            col32[e] = c;
            if ((unsigned)r < uN && (unsigned)c < uN) atomicAdd(&h[r >> 7], 1);
        }
    } else {
        const int* p = (const int*)ei;
        for (int e = s + tid; e < end; e += TPB_C) {
            int r = p[e];
            int c = p[E + e];
            row32[e] = r;
            col32[e] = c;
            if ((unsigned)r < uN && (unsigned)c < uN) atomicAdd(&h[r >> 7], 1);
        }
    }
    __syncthreads();
    for (int bin = tid; bin < NB; bin += TPB_C) hist[bin * NBLK_C + b] = h[bin];
}

// ---------------------------------------------------------------------------
// K2: per-bucket exclusive scan across the NBLK_C block histograms (in place);
// emits binTotal[bin]. One block per bucket, TPB == NBLK_C.
__global__ __launch_bounds__(NBLK_C) void colscan_kernel(int* __restrict__ hist,
                                                         int* __restrict__ binTotal) {
    __shared__ int sm[NBLK_C];
    int bin = blockIdx.x;
    int tid = threadIdx.x;
    int v = hist[bin * NBLK_C + tid];
    sm[tid] = v;
    __syncthreads();
    for (int o = 1; o < NBLK_C; o <<= 1) {
        int x = (tid >= o) ? sm[tid - o] : 0;
        __syncthreads();
        sm[tid] += x;
        __syncthreads();
    }
    hist[bin * NBLK_C + tid] = sm[tid] - v;  // exclusive within bucket
    if (tid == NBLK_C - 1) binTotal[bin] = sm[NBLK_C - 1];
}

// ---------------------------------------------------------------------------
// K3: place edges into coarse buckets. Per-block LDS cursors seeded from an
// in-kernel LDS scan of binTotal (bucketStart) + per-block hist prefix;
// packed = (col<<7) | (row&127).  NB <= 1024 (scan width = TPB_C).
__global__ __launch_bounds__(TPB_C) void scatter_kernel(const int* __restrict__ row32,
                                                        const int* __restrict__ col32, int E,
                                                        int CH,
                                                        const int* __restrict__ hist,
                                                        const int* __restrict__ binTotal,
                                                        int* __restrict__ bucketed,
                                                        int NB, int N) {
    __shared__ int cur[MAX_NB];
    __shared__ int sm2[TPB_C];
    int tid = threadIdx.x;
    int b = blockIdx.x;

    // exclusive scan of binTotal (3KB, L2-hot) -> bucketStart, fused in-LDS
    int v = (tid < NB) ? binTotal[tid] : 0;
    sm2[tid] = v;
    __syncthreads();
    for (int o = 1; o < TPB_C; o <<= 1) {
        int x = (tid >= o) ? sm2[tid - o] : 0;
        __syncthreads();
        sm2[tid] += x;
        __syncthreads();
    }
    if (tid < NB) cur[tid] = (sm2[tid] - v) + hist[tid * NBLK_C + b];
    __syncthreads();

    int s = b * CH;
    int end = min(E, s + CH);
    unsigned uN = (unsigned)N;
    for (int e = s + tid; e < end; e += TPB_C) {
        int r = row32[e];
        int c = col32[e];
        if ((unsigned)r < uN && (unsigned)c < uN) {
            int pos = atomicAdd(&cur[r >> 7], 1);
            bucketed[pos] = (c << 7) | (r & 127);
        }
    }
}

// ---------------------------------------------------------------------------
// K4: fine counting sort inside each 128-row bucket. bucketStart recomputed
// locally (tree-reduce over binTotal[0..bin)). Emits offs/cnt/dis and the
// final csr segment (all LDS atomics).
__global__ __launch_bounds__(TPB) void finecsr_kernel(const int* __restrict__ bucketed,
                                                      const int* __restrict__ binTotal,
                                                      int* __restrict__ offs,
                                                      int* __restrict__ cnt,
                                                      float* __restrict__ dis,
                                                      int* __restrict__ csr, int N) {
    __shared__ int c128[128];
    __shared__ int cur128[128];
    __shared__ int sm[TPB];
    __shared__ int red[TPB];
    int bin = blockIdx.x;
    int tid = threadIdx.x;

    // s = sum(binTotal[0..bin)) ; m = binTotal[bin]
    int part = 0;
    for (int i = tid; i < bin; i += TPB) part += binTotal[i];
    red[tid] = part;
    __syncthreads();
    for (int o = TPB / 2; o > 0; o >>= 1) {
        if (tid < o) red[tid] += red[tid + o];
        __syncthreads();
    }
    int s = red[0];
    int m = binTotal[bin];

    if (tid < 128) c128[tid] = 0;
    __syncthreads();
    for (int i = tid; i < m; i += TPB) atomicAdd(&c128[bucketed[s + i] & 127], 1);
    __syncthreads();

    int v = (tid < 128) ? c128[tid] : 0;
    sm[tid] = v;
    __syncthreads();
    for (int o = 1; o < 128; o <<= 1) {
        int x = (tid >= o) ? sm[tid - o] : 0;
        __syncthreads();
        sm[tid] += x;
        __syncthreads();
    }
    if (tid < 128) {
        int excl = sm[tid] - v;
        int r = bin * 128 + tid;
        if (r < N) {
            offs[r] = s + excl;
            cnt[r] = v;
            dis[r] = rsqrtf((float)v + 1.0f);
        }
        cur128[tid] = s + excl;
    }
    __syncthreads();
    for (int i = tid; i < m; i += TPB) {
        int p = bucketed[s + i];
        int pos = atomicAdd(&cur128[p & 127], 1);
        csr[pos] = p >> 7;
    }
}

// ---------------------------------------------------------------------------
// MFMA bf16 GEMM: Hb[r, :] = bf16( dis[r] * (X[r,:] @ W^T + b) ),  K = 128.
// BM=128 rows/block, BN = 128 or 64 cols. X (fp32 or bf16) and W (fp32) are
// cast to bf16 and staged in LDS with row stride 136 shorts (272 B) so the
// per-fragment ds_read_b128 spreads evenly over all 32 banks.
// Block 0 additionally zeroes sentinel row N (agg's tail edges gather it).
// 4 waves: BN=128 -> each wave 64x64 (4x4 16x16 tiles); BN=64 -> 32x64 (2x4).
// Fragment layouts (verified, cdna_hip_programming §3):
//   A[m=lane&15][k=(lane>>4)*8+j], B[n=lane&15][k=(lane>>4)*8+j],
//   D: col=lane&15, row=(lane>>4)*4+reg.
template <int BN, bool INB16>
__global__ __launch_bounds__(256, 2) void gemm_mfma_kernel(const void* __restrict__ Xp,
                                                           const float* __restrict__ W,
                                                           const float* __restrict__ bias,
                                                           const float* __restrict__ dis,
                                                           unsigned short* __restrict__ Hb,
                                                           int N) {
    constexpr int XST = 136;  // padded LDS row stride (shorts); 272 B ≡ 4 banks shift/row
    __shared__ unsigned short Xs[128 * XST];
    __shared__ unsigned short Ws[BN * XST];

    const int tid = threadIdx.x;
    const int r0 = blockIdx.x * 128;

    // sentinel row N = 0 (BN/2 dwords)
    if (blockIdx.x == 0 && tid < (BN >> 1))
        ((unsigned*)Hb)[(size_t)N * (BN >> 1) + tid] = 0u;

    // ---- stage X tile (128 x 128) as bf16
    if (INB16) {
        const ushort4* Xv = (const ushort4*)Xp;
        for (int idx = tid; idx < 128 * 32; idx += 256) {
            int row = idx >> 5, q = idx & 31;
            int rg = r0 + row;
            if (rg >= N) rg = N - 1;
            *(ushort4*)&Xs[row * XST + q * 4] = Xv[(size_t)rg * 32 + q];
        }
    } else {
        const float4* Xv = (const float4*)Xp;
        for (int idx = tid; idx < 128 * 32; idx += 256) {
            int row = idx >> 5, q = idx & 31;
            int rg = r0 + row;
            if (rg >= N) rg = N - 1;
            float4 v = Xv[(size_t)rg * 32 + q];
            ushort4 s = make_ushort4(f2bf(v.x), f2bf(v.y), f2bf(v.z), f2bf(v.w));
            *(ushort4*)&Xs[row * XST + q * 4] = s;
        }
    }
    // ---- stage W tile (BN x 128) as bf16
    {
        const float4* Wv = (const float4*)W;
        for (int idx = tid; idx < BN * 32; idx += 256) {
            int n = idx >> 5, q = idx & 31;
            float4 v = Wv[n * 32 + q];
            ushort4 s = make_ushort4(f2bf(v.x), f2bf(v.y), f2bf(v.z), f2bf(v.w));
            *(ushort4*)&Ws[n * XST + q * 4] = s;
        }
    }
    __syncthreads();

    constexpr int RT = (BN == 128) ? 4 : 2;  // 16-row tiles per wave
    constexpr int CT = 4;                    // 16-col tiles per wave
    const int wave = tid >> 6, lane = tid & 63;
    const int l15 = lane & 15, q8 = lane >> 4;
    const int row0 = (BN == 128) ? (wave & 1) * 64 : wave * 32;
    const int col0 = (BN == 128) ? (wave >> 1) * 64 : 0;

    f32x4 zero = {0.f, 0.f, 0.f, 0.f};
    f32x4 acc[RT][CT];
#pragma unroll
    for (int rt = 0; rt < RT; ++rt)
#pragma unroll
        for (int ct = 0; ct < CT; ++ct) acc[rt][ct] = zero;

#pragma unroll
    for (int ks = 0; ks < 4; ++ks) {
        int ko = ks * 32 + q8 * 8;
        bf16x8 a[RT], b[CT];
#pragma unroll
        for (int rt = 0; rt < RT; ++rt)
            a[rt] = *(const bf16x8*)&Xs[(row0 + rt * 16 + l15) * XST + ko];
#pragma unroll
        for (int ct = 0; ct < CT; ++ct)
            b[ct] = *(const bf16x8*)&Ws[(col0 + ct * 16 + l15) * XST + ko];
#pragma unroll
        for (int rt = 0; rt < RT; ++rt)
#pragma unroll
            for (int ct = 0; ct < CT; ++ct)
                acc[rt][ct] = __builtin_amdgcn_mfma_f32_16x16x32_bf16(
                    a[rt], b[ct], acc[rt][ct], 0, 0, 0);
    }

    // ---- epilogue: (+bias[col]) * dis[row], pack bf16
    float bv[CT];
#pragma unroll
    for (int ct = 0; ct < CT; ++ct) bv[ct] = bias[col0 + ct * 16 + l15];
#pragma unroll
    for (int rt = 0; rt < RT; ++rt)
#pragma unroll
        for (int r = 0; r < 4; ++r) {
            int row = r0 + row0 + rt * 16 + q8 * 4 + r;
            if (row < N) {
                float dn = dis[row];
#pragma unroll
                for (int ct = 0; ct < CT; ++ct)
                    Hb[(size_t)row * BN + col0 + ct * 16 + l15] =
                        f2bf((acc[rt][ct][r] + bv[ct]) * dn);
            }
        }
}

// ---------------------------------------------------------------------------
// Pull aggregation over pre-scaled bf16 H' (H'[n] = dis[n]*(XW+b)[n]):
//   out[i] = dis[i] * (H'[i] + sum_e H'[col_e]),  optional relu.
// v3: one wave per node; lane = 16*g + fl (g = edge subgroup, fl = feature
// granule). 16 lanes x 16B (8B) cover a full source row; 4 edges per load
// instr. Tail edges gather sentinel row N (zeroed by gemm) -> NO mask math,
// plain packed adds (v_pk_add_f32: 3 VALU/dword). Self row loaded by group 0
// only (exec-masked). Two 16-edge steps issued back-to-back (8 loads in
// flight; ~half the rows have d>16). Cross-group shfl_xor butterfly folds.
// OB16: pack output to bf16 (for R1 feeding the bf16 MFMA gemm2).
template <int F, bool RELU, bool OB16>
__global__ __launch_bounds__(TPB) void agg_kernel(const unsigned short* __restrict__ Hb,
                                                  const int* __restrict__ csr,
                                                  const int* __restrict__ offs,
                                                  const int* __restrict__ cnt,
                                                  const float* __restrict__ dis,
                                                  void* __restrict__ outp, int N) {
    constexpr int FPL = F / 16;      // features per lane (8 or 4)
    constexpr int NW = FPL / 2;      // dwords per lane (4 or 2)
    constexpr int RS = F / 2;        // row stride in dwords (64 or 32)

    int w = (blockIdx.x * TPB + threadIdx.x) >> 6;
    if (w >= N) return;  // wave-uniform: whole wave exits together
    int lane = threadIdx.x & 63;
    int g = lane >> 4;               // edge subgroup
    int fl = lane & 15;              // feature-granule index

    float di = dis[w];
    int s = offs[w];
    int d = cnt[w];

    const unsigned* Hu = (const unsigned*)Hb;

    f32x2 acc2[NW];
#pragma unroll
    for (int t = 0; t < NW; ++t) acc2[t] = (f32x2){0.f, 0.f};

    auto accum_row = [&](const unsigned (&u)[NW]) {
#pragma unroll
        for (int t = 0; t < NW; ++t) {
            f32x2 lh;
            lh.x = bf16lo(u[t]);
            lh.y = bf16hi(u[t]);
            acc2[t] = pk_add(acc2[t], lh);
        }
    };
    auto load_row = [&](unsigned (&u)[NW], int r) {
        if constexpr (NW == 4) {
            uint4 v = *(const uint4*)(Hu + (size_t)r * RS + fl * NW);
            u[0] = v.x; u[1] = v.y; u[2] = v.z; u[3] = v.w;
        } else {
            uint2 v = *(const uint2*)(Hu + (size_t)r * RS + fl * NW);
            u[0] = v.x; u[1] = v.y;
        }
    };

    // ---- self term: group 0 only (other groups contribute 0)
    if (g == 0) {
        unsigned su[NW];
        load_row(su, w);
        accum_row(su);
    }

    for (int base = 0; base < d; base += 64) {
        int rem = d - base;
        if (rem > 64) rem = 64;
        int cl = (lane < rem) ? csr[s + base + lane] : 0;  // coalesced chunk load

        for (int e = 0; e < rem; e += 32) {  // 2x16 edges, 8 loads in flight
            int cc0[4];
#pragma unroll
            for (int k = 0; k < 4; ++k) {
                int idx = e + k * 4 + g;
                int raw = __shfl(cl, idx & 63);
                cc0[k] = (idx < rem) ? raw : N;   // tail -> zero sentinel row
            }
            unsigned u0[4][NW];
#pragma unroll
            for (int k = 0; k < 4; ++k) load_row(u0[k], cc0[k]);

            const bool two = (e + 16) < rem;     // wave-uniform
            int cc1[4];
            unsigned u1[4][NW];
            if (two) {
#pragma unroll
                for (int k = 0; k < 4; ++k) {
                    int idx = e + 16 + k * 4 + g;
                    int raw = __shfl(cl, idx & 63);
                    cc1[k] = (idx < rem) ? raw : N;
                }
#pragma unroll
                for (int k = 0; k < 4; ++k) load_row(u1[k], cc1[k]);
            }
#pragma unroll
            for (int k = 0; k < 4; ++k) accum_row(u0[k]);
            if (two) {
#pragma unroll
                for (int k = 0; k < 4; ++k) accum_row(u1[k]);
            }
        }
    }

    // ---- fold the 4 edge-subgroups (lanes fl, fl+16, fl+32, fl+48 share features)
#pragma unroll
    for (int off = 16; off < 64; off <<= 1)
#pragma unroll
        for (int t = 0; t < NW; ++t) {
            acc2[t].x += __shfl_xor(acc2[t].x, off);
            acc2[t].y += __shfl_xor(acc2[t].y, off);
        }

#pragma unroll
    for (int t = 0; t < NW; ++t) {
        acc2[t].x *= di;
        acc2[t].y *= di;
        if (RELU) {
            acc2[t].x = fmaxf(acc2[t].x, 0.0f);
            acc2[t].y = fmaxf(acc2[t].y, 0.0f);
        }
    }

    // ---- store: lanes 0..15 hold the full row (256B / 128B contiguous)
    if (lane < 16) {
        if constexpr (OB16) {
            unsigned dw[NW];
#pragma unroll
            for (int t = 0; t < NW; ++t)
                dw[t] = (unsigned)f2bf(acc2[t].x) | ((unsigned)f2bf(acc2[t].y) << 16);
            unsigned* op = (unsigned*)outp;
            if constexpr (NW == 4) {
                *(uint4*)&op[(size_t)w * RS + fl * NW] = make_uint4(dw[0], dw[1], dw[2], dw[3]);
            } else {
                *(uint2*)&op[(size_t)w * RS + fl * NW] = make_uint2(dw[0], dw[1]);
            }
        } else {
            float4* op = (float4*)outp;
            if constexpr (NW == 2) {
                op[(size_t)w * 16 + fl] =
                    make_float4(acc2[0].x, acc2[0].y, acc2[1].x, acc2[1].y);
            } else {
                op[(size_t)w * 32 + fl * 2] =
                    make_float4(acc2[0].x, acc2[0].y, acc2[1].x, acc2[1].y);
                op[(size_t)w * 32 + fl * 2 + 1] =
                    make_float4(acc2[2].x, acc2[2].y, acc2[3].x, acc2[3].y);
            }
        }
    }
}

// ---------------------------------------------------------------------------
extern "C" void kernel_launch(void* const* d_in, const int* in_sizes, int n_in,
                              void* d_out, int out_size, void* d_ws, size_t ws_size,
                              hipStream_t stream) {
    const float* x  = (const float*)d_in[0];
    const void*  ei = d_in[1];
    const float* W1 = (const float*)d_in[3];
    const float* b1 = (const float*)d_in[4];
    const float* W2 = (const float*)d_in[5];
    const float* b2 = (const float*)d_in[6];
    float* out = (float*)d_out;

    const int IN = 128, HID = 128;
    const int N = in_sizes[0] / IN;
    const int E = in_sizes[1] / 2;
    const int NB = (N + 127) >> 7;                 // coarse buckets (rows/128)
    const int CH = (E + NBLK_C - 1) / NBLK_C;      // edges per chunk block

    char* ws = (char*)d_ws;
    size_t off = 0;
    auto alloc = [&](size_t bytes) -> void* {
        void* p = (void*)(ws + off);
        off += (bytes + 255) & ~(size_t)255;
        return p;
    };
    int*   cnt      = (int*)alloc((size_t)N * 4);
    int*   offs     = (int*)alloc((size_t)N * 4);
    float* dis      = (float*)alloc((size_t)N * 4);
    int*   row32    = (int*)alloc((size_t)E * 4);
    int*   col32    = (int*)alloc((size_t)E * 4);
    int*   bucketed = (int*)alloc((size_t)E * 4);
    int*   csr      = (int*)alloc((size_t)E * 4);
    int*   hist     = (int*)alloc((size_t)NB * NBLK_C * 4);
    int*   binTotal = (int*)alloc((size_t)NB * 4);
    unsigned short* H1b = (unsigned short*)alloc((size_t)(N + 1) * HID * 2);  // bf16 (+sentinel)
    unsigned short* R1b = (unsigned short*)alloc((size_t)(N + 1) * HID * 2);  // bf16
    unsigned short* H2b = H1b;  // reuse: H1b dead after agg1

    // ---- CSR build: counting sort, zero global atomics (4 launches)
    hist_extract_kernel<<<NBLK_C, TPB_C, 0, stream>>>(ei, E, CH, row32, col32,
                                                      hist, NB, N);
    colscan_kernel<<<NB, NBLK_C, 0, stream>>>(hist, binTotal);
    scatter_kernel<<<NBLK_C, TPB_C, 0, stream>>>(row32, col32, E, CH, hist, binTotal,
                                                 bucketed, NB, N);
    finecsr_kernel<<<NB, TPB, 0, stream>>>(bucketed, binTotal, offs, cnt, dis, csr, N);

    int ngrid = (N + 127) / 128;

    // layer 1: H1b = bf16(dis .* (X@W1^T + b1)) ; R1b = bf16(relu(dis .* (self+gather)))
    gemm_mfma_kernel<128, false><<<ngrid, 256, 0, stream>>>(x, W1, b1, dis, H1b, N);
    agg_kernel<128, true, true><<<(N + 3) / 4, TPB, 0, stream>>>(H1b, csr, offs, cnt,
                                                                 dis, R1b, N);

    // layer 2: H2b = bf16(dis .* (R1b@W2^T + b2)) ; out = dis .* (self + gather)
    gemm_mfma_kernel<64, true><<<ngrid, 256, 0, stream>>>(R1b, W2, b2, dis, H2b, N);
    agg_kernel<64, false, false><<<(N + 3) / 4, TPB, 0, stream>>>(H2b, csr, offs, cnt,
                                                                  dis, out, N);
}